// Round 1
// baseline (744.780 us; speedup 1.0000x reference)
//
#include <hip/hip_runtime.h>
#include <cmath>

#define VOCAB 50257
#define HDIM 2048

__device__ __forceinline__ float4 ld4(const float* p) {
    return *reinterpret_cast<const float4*>(p);
}
__device__ __forceinline__ float dot4(float4 a, float4 b) {
    return a.x * b.x + a.y * b.y + a.z * b.z + a.w * b.w;
}

// Block j computes h[j]: 6 dot products of length HDIM (rows j, j+H, j+2H of
// weightx against relu(emb_row), and of weighth against hidden), then gates.
__global__ __launch_bounds__(256) void gru_gates_kernel(
    const int* __restrict__ ic,
    const float* __restrict__ hidden,
    const float* __restrict__ emb,
    const float* __restrict__ wx,
    const float* __restrict__ wh,
    const float* __restrict__ bx,
    const float* __restrict__ bh,
    float* __restrict__ h_out)
{
    const int j = blockIdx.x;
    const int t = threadIdx.x;
    const int lane = t & 63;
    const int wv = t >> 6;

    const float* erow = emb + (size_t)ic[0] * HDIM;
    const int o0 = t * 4;          // 2048 floats / 256 threads = 8 floats = 2x float4
    const int o1 = o0 + 1024;

    float4 e0 = ld4(erow + o0), e1 = ld4(erow + o1);
    e0.x = fmaxf(e0.x, 0.f); e0.y = fmaxf(e0.y, 0.f);
    e0.z = fmaxf(e0.z, 0.f); e0.w = fmaxf(e0.w, 0.f);
    e1.x = fmaxf(e1.x, 0.f); e1.y = fmaxf(e1.y, 0.f);
    e1.z = fmaxf(e1.z, 0.f); e1.w = fmaxf(e1.w, 0.f);
    float4 h0 = ld4(hidden + o0), h1 = ld4(hidden + o1);

    float acc[6];
    #pragma unroll
    for (int k = 0; k < 3; ++k) {
        const float* wxr = wx + (size_t)(j + k * HDIM) * HDIM;
        const float* whr = wh + (size_t)(j + k * HDIM) * HDIM;
        acc[k]     = dot4(e0, ld4(wxr + o0)) + dot4(e1, ld4(wxr + o1));
        acc[3 + k] = dot4(h0, ld4(whr + o0)) + dot4(h1, ld4(whr + o1));
    }

    // wave reduce all 6 accumulators
    #pragma unroll
    for (int s = 32; s > 0; s >>= 1) {
        #pragma unroll
        for (int k = 0; k < 6; ++k) acc[k] += __shfl_down(acc[k], s, 64);
    }

    __shared__ float red[6][4];
    if (lane == 0) {
        #pragma unroll
        for (int k = 0; k < 6; ++k) red[k][wv] = acc[k];
    }
    __syncthreads();

    if (t == 0) {
        float sx0 = red[0][0] + red[0][1] + red[0][2] + red[0][3];
        float sx1 = red[1][0] + red[1][1] + red[1][2] + red[1][3];
        float sx2 = red[2][0] + red[2][1] + red[2][2] + red[2][3];
        float sh0 = red[3][0] + red[3][1] + red[3][2] + red[3][3];
        float sh1 = red[4][0] + red[4][1] + red[4][2] + red[4][3];
        float sh2 = red[5][0] + red[5][1] + red[5][2] + red[5][3];

        float xs_r = sx0 + bx[j];
        float xs_z = sx1 + bx[j + HDIM];
        float xs_n = sx2 + bx[j + 2 * HDIM];
        float hs_r = sh0 + bh[j];
        float hs_z = sh1 + bh[j + HDIM];
        float hs_n = sh2 + bh[j + 2 * HDIM];

        float r = 1.f / (1.f + expf(-(xs_r + hs_r)));
        float z = 1.f / (1.f + expf(-(xs_z + hs_z)));
        float n = tanhf(xs_n + r * hs_n);
        h_out[j] = (1.f - z) * n + z * hidden[j];
    }
}

// One wave per vocab row; 4 waves (4 rows) per block.
__global__ __launch_bounds__(256) void logits_kernel(
    const float* __restrict__ h,
    const float* __restrict__ W,
    const float* __restrict__ b,
    float* __restrict__ out)
{
    const int lane = threadIdx.x & 63;
    const int wv = threadIdx.x >> 6;
    const int row = blockIdx.x * 4 + wv;
    if (row >= VOCAB) return;

    const float* wr = W + (size_t)row * HDIM;
    float acc = 0.f;
    #pragma unroll
    for (int c = 0; c < 8; ++c) {
        const int off = c * 256 + lane * 4;   // 64 lanes x 16B = 1KB contiguous per chunk
        acc += dot4(ld4(wr + off), ld4(h + off));
    }
    #pragma unroll
    for (int s = 32; s > 0; s >>= 1) acc += __shfl_down(acc, s, 64);
    if (lane == 0) out[row] = acc + b[row];
}

// 64 blocks x 256 threads: online (max, sumexp) -> one pair per block in ws.
__global__ __launch_bounds__(256) void softmax_reduce_kernel(
    const float* __restrict__ logits, float* __restrict__ pairs)
{
    const int t = blockIdx.x * 256 + threadIdx.x;   // 16384 threads, all get >=1 elem
    const int lane = threadIdx.x & 63;
    const int wv = threadIdx.x >> 6;

    float m = -INFINITY, sv = 0.f;
    for (int i = t; i < VOCAB; i += 64 * 256) {
        float x = logits[i];
        if (x > m) { sv = sv * expf(m - x) + 1.f; m = x; }
        else       { sv += expf(x - m); }
    }
    #pragma unroll
    for (int s = 32; s > 0; s >>= 1) {
        float m2 = __shfl_down(m, s, 64);
        float s2 = __shfl_down(sv, s, 64);
        float M = fmaxf(m, m2);
        sv = sv * expf(m - M) + s2 * expf(m2 - M);
        m = M;
    }
    __shared__ float sm[4], ss[4];
    if (lane == 0) { sm[wv] = m; ss[wv] = sv; }
    __syncthreads();
    if (threadIdx.x == 0) {
        float M = fmaxf(fmaxf(sm[0], sm[1]), fmaxf(sm[2], sm[3]));
        float S = ss[0] * expf(sm[0] - M) + ss[1] * expf(sm[1] - M)
                + ss[2] * expf(sm[2] - M) + ss[3] * expf(sm[3] - M);
        pairs[2 * blockIdx.x]     = M;
        pairs[2 * blockIdx.x + 1] = S;
    }
}

// Each block redundantly combines the 64 pairs (2KB, L2-hit), then subtracts.
__global__ __launch_bounds__(256) void finalize_kernel(
    const float* __restrict__ pairs, float* __restrict__ out)
{
    __shared__ float sC;
    if (threadIdx.x < 64) {
        float m = pairs[2 * threadIdx.x];
        float s = pairs[2 * threadIdx.x + 1];
        #pragma unroll
        for (int sh = 32; sh > 0; sh >>= 1) {
            float m2 = __shfl_down(m, sh, 64);
            float s2 = __shfl_down(s, sh, 64);
            float M = fmaxf(m, m2);
            s = s * expf(m - M) + s2 * expf(m2 - M);
            m = M;
        }
        if (threadIdx.x == 0) sC = m + logf(s);
    }
    __syncthreads();
    const float C = sC;
    const int i = blockIdx.x * 256 + threadIdx.x;
    if (i < VOCAB) out[i] -= C;
}

extern "C" void kernel_launch(void* const* d_in, const int* in_sizes, int n_in,
                              void* d_out, int out_size, void* d_ws, size_t ws_size,
                              hipStream_t stream) {
    const int*   ic     = (const int*)d_in[0];
    const float* hidden = (const float*)d_in[1];
    const float* emb    = (const float*)d_in[2];
    const float* wx     = (const float*)d_in[3];
    const float* wh     = (const float*)d_in[4];
    const float* bx     = (const float*)d_in[5];
    const float* bh     = (const float*)d_in[6];
    const float* W_out  = (const float*)d_in[7];
    const float* b_out  = (const float*)d_in[8];

    float* out   = (float*)d_out;          // [0, VOCAB): log_softmax
    float* h_out = out + VOCAB;            // [VOCAB, VOCAB+HDIM): new hidden
    float* pairs = (float*)d_ws;           // 64 (max,sumexp) pairs

    gru_gates_kernel<<<HDIM, 256, 0, stream>>>(ic, hidden, emb, wx, wh, bx, bh, h_out);
    logits_kernel<<<(VOCAB + 3) / 4, 256, 0, stream>>>(h_out, W_out, b_out, out);
    softmax_reduce_kernel<<<64, 256, 0, stream>>>(out, pairs);
    finalize_kernel<<<(VOCAB + 255) / 256, 256, 0, stream>>>(pairs, out);
}